// Round 4
// baseline (240.314 us; speedup 1.0000x reference)
//
#include <hip/hip_runtime.h>
#include <math.h>

#define KK 200
#define MM 256
#define NI 199      // NE-1 increments
#define HH 16
#define TBLN 2048
#define XMAX 8.0f
#define INVH 256.0f // TBLN / XMAX  (same resolution as R3's 4096/16)

__device__ __forceinline__ float fast_tanh(float x) {
  // tanh(x) = 1 - 2/(exp(2x)+1); err ~4e-7 abs, saturates correctly
  float e = __expf(2.0f * x);
  return 1.0f - 2.0f * __builtin_amdgcn_rcpf(e + 1.0f);
}

// ---- kernel 1: in-block mu-table + scan + bridge + per-(k,m) Girsanov sum ----
__global__ __launch_bounds__(1024) void lt_main(
    const float* __restrict__ t0,
    const float* __restrict__ noise,
    const float* __restrict__ gW1, const float* __restrict__ gb1,
    const float* __restrict__ gW2, const float* __restrict__ gb2,
    const float* __restrict__ gW3, const float* __restrict__ gb3,
    float* __restrict__ s_out) {
  __shared__ float sT[TBLN];
  const int tid = threadIdx.x;

  // build mu(x) lerp table in-LDS: 2 entries per thread (one-time ~1.1k cycles)
#pragma unroll
  for (int r = 0; r < 2; ++r) {
    const int i = tid + r * 1024;
    const float x = (float)i * (XMAX / (float)TBLN);
    float h1[HH];
#pragma unroll
    for (int j = 0; j < HH; ++j) h1[j] = fast_tanh(fmaf(x, gW1[j], gb1[j]));
    float mu = gb3[0];
#pragma unroll
    for (int i2 = 0; i2 < HH; ++i2) {
      float z = gb2[i2];
#pragma unroll
      for (int j = 0; j < HH; ++j) z = fmaf(h1[j], gW2[j * HH + i2], z);
      mu = fmaf(fast_tanh(z), gW3[i2], mu);
    }
    sT[i] = mu;
  }
  __syncthreads();

  const int wave = tid >> 6, lane = tid & 63;
  const int pair = blockIdx.x * 16 + wave;     // pair = k*256 + m
  const int m = pair & 255;

  const float t0m = t0[m];
  const float dt0 = t0[m + 1] - t0m;
  const float inv199 = 1.0f / 199.0f;

  const float* nrow = noise + (size_t)pair * NI;
  const int p0 = lane * 4;

  // load 4 consecutive noise increments (masked tail)
  float nv[4];
  if (p0 + 3 < NI) {
    nv[0] = nrow[p0]; nv[1] = nrow[p0 + 1]; nv[2] = nrow[p0 + 2]; nv[3] = nrow[p0 + 3];
  } else {
#pragma unroll
    for (int c = 0; c < 4; ++c) nv[c] = (p0 + c < NI) ? nrow[p0 + c] : 0.0f;
  }

  // e_time fractions (mimic reference f32 arithmetic)
  float f[5], e[5];
#pragma unroll
  for (int c = 0; c < 5; ++c) {
    f[c] = (float)(p0 + c) * inv199;
    e[c] = t0m + f[c] * dt0;
  }

  float dte[4], cum[5];
  cum[0] = 0.0f;
#pragma unroll
  for (int c = 0; c < 4; ++c) {
    dte[c] = e[c + 1] - e[c];
    float v = (p0 + c < NI) ? nv[c] * sqrtf(dte[c]) : 0.0f;
    cum[c + 1] = cum[c] + v;
  }
  const float tot = cum[4];

  // wave-level inclusive scan of per-lane totals
  float x = tot;
#pragma unroll
  for (int off = 1; off < 64; off <<= 1) {
    float y = __shfl_up(x, off, 64);
    if (lane >= off) x += y;
  }
  const float prefix = x - tot;          // exclusive prefix = W[4*lane]
  const float Wfin = __shfl(x, 63, 64);  // W[199]

  // bridge |W - frac*Wfin| at the 5 owned points
  float xb[5];
#pragma unroll
  for (int c = 0; c < 5; ++c) xb[c] = fabsf((prefix + cum[c]) - f[c] * Wfin);

  // mu via LDS lerp table; accumulate s = sum(mu*dx - 0.5*mu^2*dt)
  float sp = 0.0f;
#pragma unroll
  for (int c = 0; c < 4; ++c) {
    if (p0 + c < NI) {
      float xc = fminf(xb[c], XMAX - 2.0f / INVH);
      float tt = xc * INVH;
      int ix = (int)tt;
      float fr = tt - (float)ix;
      float T0 = sT[ix], T1 = sT[ix + 1];
      float mu = fmaf(fr, T1 - T0, T0);
      float dx = xb[c + 1] - xb[c];
      sp += mu * dx - 0.5f * mu * mu * dte[c];
    }
  }
#pragma unroll
  for (int off = 32; off > 0; off >>= 1) sp += __shfl_xor(sp, off, 64);
  if (lane == 0) {
    int k = pair >> 8;
    s_out[m * KK + k] = sp;              // [M][K] so finish reads rows
  }
}

// ---- kernel 2: per-m logsumexp over K (coalesced, one wave per m) + mean ----
__global__ __launch_bounds__(1024) void lt_finish(
    const float* __restrict__ t0, const float* __restrict__ s_in,
    float* __restrict__ out) {
  const int tid = threadIdx.x;
  const int wave = tid >> 6, lane = tid & 63;

  float acc = 0.0f;
#pragma unroll
  for (int mm = 0; mm < 16; ++mm) {
    const int m = mm * 16 + wave;
    const float* row = s_in + m * KK;
    // lanes cover k: 64+64+64+8 coalesced
    float v0 = row[lane];
    float v1 = row[lane + 64];
    float v2 = row[lane + 128];
    float v3 = (lane < 8) ? row[lane + 192] : -INFINITY;

    float mx = fmaxf(fmaxf(v0, v1), fmaxf(v2, v3));
#pragma unroll
    for (int off = 32; off > 0; off >>= 1) mx = fmaxf(mx, __shfl_xor(mx, off, 64));

    float sum = __expf(v0 - mx) + __expf(v1 - mx) + __expf(v2 - mx)
              + ((lane < 8) ? __expf(v3 - mx) : 0.0f);
#pragma unroll
    for (int off = 32; off > 0; off >>= 1) sum += __shfl_xor(sum, off, 64);

    if (lane == 0) {
      float expect = logf(sum) + mx - logf(200.0f);
      float d = t0[m + 1] - t0[m];
      const float eps = 0.01f;
      float p = logf(eps + 1e-7f) + 0.5f * logf(0.6366197723675814f)
              - 2.0f * eps * eps / d - logf(d * sqrtf(d) + 1e-7f);
      acc += p + expect;
    }
  }

  __shared__ float red[16];
  if (lane == 0) red[wave] = acc;
  __syncthreads();
  if (tid == 0) {
    float s2 = 0.0f;
#pragma unroll
    for (int i = 0; i < 16; ++i) s2 += red[i];
    out[0] = s2 * (1.0f / 256.0f);
  }
}

extern "C" void kernel_launch(void* const* d_in, const int* in_sizes, int n_in,
                              void* d_out, int out_size, void* d_ws, size_t ws_size,
                              hipStream_t stream) {
  const float* t0    = (const float*)d_in[0];
  const float* noise = (const float*)d_in[1];
  const float* W1    = (const float*)d_in[2];
  const float* b1    = (const float*)d_in[3];
  const float* W2    = (const float*)d_in[4];
  const float* b2    = (const float*)d_in[5];
  const float* W3    = (const float*)d_in[6];
  const float* b3    = (const float*)d_in[7];

  float* s_ws = (float*)d_ws;            // [M][K] = 51200 floats (204800 B)
  float* out  = (float*)d_out;

  lt_main<<<(KK * MM) / 16, 1024, 0, stream>>>(t0, noise, W1, b1, W2, b2, W3, b3, s_ws);
  lt_finish<<<1, 1024, 0, stream>>>(t0, s_ws, out);
}

// Round 5
// 133.317 us; speedup vs baseline: 1.8026x; 1.8026x over previous
//
#include <hip/hip_runtime.h>
#include <math.h>

#define KK 200
#define MM 256
#define NI 199      // NE-1 increments
#define HH 16
#define TBLN 2048
#define XMAX 8.0f
#define INVH 256.0f // TBLN / XMAX

// ---------------- kernel 0: build mu(x) lookup table (4096 MLP evals total) ----------------
__global__ __launch_bounds__(256) void lt_table(
    const float* __restrict__ W1, const float* __restrict__ b1,
    const float* __restrict__ W2, const float* __restrict__ b2,
    const float* __restrict__ W3, const float* __restrict__ b3,
    float* __restrict__ tbl) {
  int i = blockIdx.x * 256 + threadIdx.x;
  if (i >= TBLN) return;
  float x = (float)i * (XMAX / (float)TBLN);
  float h1[HH];
#pragma unroll
  for (int j = 0; j < HH; ++j) h1[j] = tanhf(fmaf(x, W1[j], b1[j]));
  float mu = b3[0];
#pragma unroll
  for (int i2 = 0; i2 < HH; ++i2) {
    float z = b2[i2];
#pragma unroll
    for (int j = 0; j < HH; ++j) z = fmaf(h1[j], W2[j * HH + i2], z);
    mu = fmaf(tanhf(z), W3[i2], mu);
  }
  tbl[i] = mu;
}

// ---------------- kernel 1: scan + bridge + table-mu + per-(k,m) sum ----------------
__global__ __launch_bounds__(1024) void lt_main(
    const float* __restrict__ t0,
    const float* __restrict__ noise,
    const float* __restrict__ tbl,
    float* __restrict__ s_out) {
  __shared__ float sT[TBLN];
  const int tid = threadIdx.x;
#pragma unroll
  for (int i = 0; i < TBLN / 1024; ++i) sT[tid + i * 1024] = tbl[tid + i * 1024];
  __syncthreads();

  const int wave = tid >> 6, lane = tid & 63;
  const int pair = blockIdx.x * 16 + wave;     // pair = k*256 + m
  const int m = pair & 255;

  const float t0m = t0[m];
  const float dt0 = t0[m + 1] - t0m;
  const float inv199 = 1.0f / 199.0f;

  const float* nrow = noise + (size_t)pair * NI;
  const int p0 = lane * 4;

  // load 4 consecutive noise increments (masked tail)
  float nv[4];
  if (p0 + 3 < NI) {
    nv[0] = nrow[p0]; nv[1] = nrow[p0 + 1]; nv[2] = nrow[p0 + 2]; nv[3] = nrow[p0 + 3];
  } else {
#pragma unroll
    for (int c = 0; c < 4; ++c) nv[c] = (p0 + c < NI) ? nrow[p0 + c] : 0.0f;
  }

  // e_time fractions (mimic reference f32 arithmetic)
  float f[5], e[5];
#pragma unroll
  for (int c = 0; c < 5; ++c) {
    f[c] = (float)(p0 + c) * inv199;
    e[c] = t0m + f[c] * dt0;
  }

  float dte[4], cum[5];
  cum[0] = 0.0f;
#pragma unroll
  for (int c = 0; c < 4; ++c) {
    dte[c] = e[c + 1] - e[c];
    float v = (p0 + c < NI) ? nv[c] * sqrtf(dte[c]) : 0.0f;
    cum[c + 1] = cum[c] + v;
  }
  const float tot = cum[4];

  // wave-level inclusive scan of per-lane totals
  float x = tot;
#pragma unroll
  for (int off = 1; off < 64; off <<= 1) {
    float y = __shfl_up(x, off, 64);
    if (lane >= off) x += y;
  }
  const float prefix = x - tot;          // exclusive prefix = W[4*lane]
  const float Wfin = __shfl(x, 63, 64);  // W[199]

  // bridge |W - frac*Wfin| at the 5 owned points
  float xb[5];
#pragma unroll
  for (int c = 0; c < 5; ++c) xb[c] = fabsf((prefix + cum[c]) - f[c] * Wfin);

  // mu via LDS lerp table; accumulate s = sum(mu*dx - 0.5*mu^2*dt)
  float sp = 0.0f;
#pragma unroll
  for (int c = 0; c < 4; ++c) {
    if (p0 + c < NI) {
      float xc = fminf(xb[c], XMAX - 2.0f / INVH);
      float tt = xc * INVH;
      int ix = (int)tt;
      float fr = tt - (float)ix;
      float T0 = sT[ix], T1 = sT[ix + 1];
      float mu = fmaf(fr, T1 - T0, T0);
      float dx = xb[c + 1] - xb[c];
      sp += mu * dx - 0.5f * mu * mu * dte[c];
    }
  }
#pragma unroll
  for (int off = 32; off > 0; off >>= 1) sp += __shfl_xor(sp, off, 64);
  if (lane == 0) {
    int k = pair >> 8;
    s_out[m * KK + k] = sp;              // [M][K] so finish reads rows coalesced
  }
}

// ---- kernel 2: per-m logsumexp over K (coalesced, one wave per m) + mean ----
__global__ __launch_bounds__(1024) void lt_finish(
    const float* __restrict__ t0, const float* __restrict__ s_in,
    float* __restrict__ out) {
  const int tid = threadIdx.x;
  const int wave = tid >> 6, lane = tid & 63;

  float acc = 0.0f;
#pragma unroll
  for (int mm = 0; mm < 16; ++mm) {
    const int m = mm * 16 + wave;
    const float* row = s_in + m * KK;
    // lanes cover k: 64+64+64+8 coalesced
    float v0 = row[lane];
    float v1 = row[lane + 64];
    float v2 = row[lane + 128];
    float v3 = (lane < 8) ? row[lane + 192] : -INFINITY;

    float mx = fmaxf(fmaxf(v0, v1), fmaxf(v2, v3));
#pragma unroll
    for (int off = 32; off > 0; off >>= 1) mx = fmaxf(mx, __shfl_xor(mx, off, 64));

    float sum = __expf(v0 - mx) + __expf(v1 - mx) + __expf(v2 - mx)
              + ((lane < 8) ? __expf(v3 - mx) : 0.0f);
#pragma unroll
    for (int off = 32; off > 0; off >>= 1) sum += __shfl_xor(sum, off, 64);

    if (lane == 0) {
      float expect = logf(sum) + mx - logf(200.0f);
      float d = t0[m + 1] - t0[m];
      const float eps = 0.01f;
      float p = logf(eps + 1e-7f) + 0.5f * logf(0.6366197723675814f)
              - 2.0f * eps * eps / d - logf(d * sqrtf(d) + 1e-7f);
      acc += p + expect;
    }
  }

  __shared__ float red[16];
  if (lane == 0) red[wave] = acc;
  __syncthreads();
  if (tid == 0) {
    float s2 = 0.0f;
#pragma unroll
    for (int i = 0; i < 16; ++i) s2 += red[i];
    out[0] = s2 * (1.0f / 256.0f);
  }
}

extern "C" void kernel_launch(void* const* d_in, const int* in_sizes, int n_in,
                              void* d_out, int out_size, void* d_ws, size_t ws_size,
                              hipStream_t stream) {
  const float* t0    = (const float*)d_in[0];
  const float* noise = (const float*)d_in[1];
  const float* W1    = (const float*)d_in[2];
  const float* b1    = (const float*)d_in[3];
  const float* W2    = (const float*)d_in[4];
  const float* b2    = (const float*)d_in[5];
  const float* W3    = (const float*)d_in[6];
  const float* b3    = (const float*)d_in[7];

  float* s_ws = (float*)d_ws;            // [M][K] = 51200 floats (204800 B)
  float* tbl  = s_ws + KK * MM;          // 2048 floats (8192 B)
  float* out  = (float*)d_out;

  lt_table<<<TBLN / 256, 256, 0, stream>>>(W1, b1, W2, b2, W3, b3, tbl);
  lt_main<<<(KK * MM) / 16, 1024, 0, stream>>>(t0, noise, tbl, s_ws);
  lt_finish<<<1, 1024, 0, stream>>>(t0, s_ws, out);
}